// Round 1
// baseline (172.898 us; speedup 1.0000x reference)
//
#include <hip/hip_runtime.h>

#define RANK 16
#define N 512
#define BTILE 32

__global__ __launch_bounds__(128) void parafac_kernel(
    const float* __restrict__ f0,
    const float* __restrict__ f1,
    const float* __restrict__ f2,
    float* __restrict__ out)
{
    // grid.x = N * (N / BTILE); 128 threads; thread t owns c in [4t, 4t+4)
    const int blk = blockIdx.x;
    const int a  = blk / (N / BTILE);
    const int b0 = (blk % (N / BTILE)) * BTILE;
    const int tid = threadIdx.x;
    const int c4 = tid * 4;

    // Preload f0 column a (wave-uniform scalars)
    float f0a[RANK];
#pragma unroll
    for (int k = 0; k < RANK; ++k) f0a[k] = f0[k * N + a];

    // Preload f2 fragment: 16 x float4 in registers (64 VGPRs)
    float4 v[RANK];
#pragma unroll
    for (int k = 0; k < RANK; ++k)
        v[k] = *reinterpret_cast<const float4*>(&f2[k * N + c4]);

    float* outrow = out + ((size_t)a * N + b0) * N + c4;

#pragma unroll 4
    for (int bi = 0; bi < BTILE; ++bi) {
        const int b = b0 + bi;
        float4 acc = make_float4(0.f, 0.f, 0.f, 0.f);
#pragma unroll
        for (int k = 0; k < RANK; ++k) {
            const float p = f0a[k] * f1[k * N + b];  // uniform -> s_load expected
            acc.x = fmaf(p, v[k].x, acc.x);
            acc.y = fmaf(p, v[k].y, acc.y);
            acc.z = fmaf(p, v[k].z, acc.z);
            acc.w = fmaf(p, v[k].w, acc.w);
        }
        *reinterpret_cast<float4*>(outrow + (size_t)bi * N) = acc;
    }
}

extern "C" void kernel_launch(void* const* d_in, const int* in_sizes, int n_in,
                              void* d_out, int out_size, void* d_ws, size_t ws_size,
                              hipStream_t stream) {
    const float* f0 = (const float*)d_in[0];
    const float* f1 = (const float*)d_in[1];
    const float* f2 = (const float*)d_in[2];
    float* out = (float*)d_out;

    dim3 grid(N * (N / BTILE));  // 512 * 16 = 8192 blocks
    dim3 block(128);
    parafac_kernel<<<grid, block, 0, stream>>>(f0, f1, f2, out);
}